// Round 1
// baseline (595.855 us; speedup 1.0000x reference)
//
#include <hip/hip_runtime.h>
#include <math.h>

// Problem sizes (fixed by reference)
#define D   2048
#define H   2048
#define K0  16
#define KJ  8

// ---- workspace layout (in floats) ----
// assign[16]
#define WS_ASSIGN  0
// gate[16][8]
#define WS_GATE    64
// c_leaf[16][2048]
#define WS_CLEAF   256
// pleaf[16 dc][16 k][2048 h]
#define WS_PLEAF   33280
// pnl[8 hc][8 j][16 k][2048 g]
#define WS_PNL     557568
// c_no_leaf[8][2048]
#define WS_CNL     2654720
// proot[32 gc][8 j][2048 g2]
#define WS_PROOT   2671104
// total = 3,195,392 floats = 12.8 MB

// ---------------- K1: soft assignment (softmax over -||x-c||^2/10) ----------
__global__ void k_assign(const float* __restrict__ x, const float* __restrict__ cc,
                         float* __restrict__ ws) {
    __shared__ float red[256];
    __shared__ float sq[K0];
    int t = threadIdx.x;
    for (int k = 0; k < K0; ++k) {
        float a = 0.f;
        for (int d = t; d < D; d += 256) {
            float df = x[d] - cc[k * D + d];
            a += df * df;
        }
        red[t] = a; __syncthreads();
        for (int s = 128; s > 0; s >>= 1) {
            if (t < s) red[t] += red[t + s];
            __syncthreads();
        }
        if (t == 0) sq[k] = red[0];
        __syncthreads();
    }
    if (t == 0) {
        float m = -1e30f;
        for (int k = 0; k < K0; ++k) {
            float v = -sq[k] * 0.1f;   // -sq/(2*sigma), sigma=5
            sq[k] = v;
            m = fmaxf(m, v);
        }
        float s = 0.f;
        for (int k = 0; k < K0; ++k) { sq[k] = expf(sq[k] - m); s += sq[k]; }
        float inv = 1.0f / s;
        for (int k = 0; k < K0; ++k) ws[WS_ASSIGN + k] = sq[k] * inv;
    }
}

// ------------- K2: leaf einsum partials: x @ leaf_weight_u[k] ---------------
// grid (16 k, 2 h-tiles, 16 d-chunks), 256 threads, each thread owns 4 h (float4)
__global__ void k_leaf_partial(const float* __restrict__ x, const float* __restrict__ W,
                               float* __restrict__ ws) {
    const int k  = blockIdx.x;
    const int h0 = blockIdx.y * 1024;
    const int dc = blockIdx.z;
    const int d0 = dc * 128;
    __shared__ float xs[128];
    int t = threadIdx.x;
    if (t < 128) xs[t] = x[d0 + t];
    __syncthreads();
    int h = h0 + t * 4;
    const float* Wp = W + ((size_t)k * D + d0) * (size_t)H + h;
    float4 acc = make_float4(0.f, 0.f, 0.f, 0.f);
#pragma unroll 8
    for (int dd = 0; dd < 128; ++dd) {
        float4 w = *(const float4*)(Wp + (size_t)dd * H);
        float xv = xs[dd];
        acc.x += xv * w.x; acc.y += xv * w.y; acc.z += xv * w.z; acc.w += xv * w.w;
    }
    *(float4*)(ws + WS_PLEAF + ((size_t)(dc * K0 + k)) * H + h) = acc;
}

// ------------- K3a: reduce partials -> c_leaf = assign*tanh(.+bias) ---------
__global__ void k_cleaf(const float* __restrict__ lb, float* __restrict__ ws) {
    int idx = blockIdx.x * 256 + threadIdx.x;   // 128 blocks -> 32768
    int k = idx >> 11;
    int h = idx & (H - 1);
    float s = 0.f;
#pragma unroll
    for (int dc = 0; dc < 16; ++dc)
        s += ws[WS_PLEAF + ((size_t)(dc * K0 + k) << 11) + h];
    float v = tanhf(s + lb[k * H + h]) * ws[WS_ASSIGN + k];
    ws[WS_CLEAF + k * H + h] = v;
}

// ------------- K3b: gate = softmax_j(c_leaf[k] . Wi[j] + bi[j]) -------------
__global__ void k_gate(const float* __restrict__ Wi, const float* __restrict__ bi,
                       float* __restrict__ ws) {
    int k = blockIdx.x;    // 16 blocks
    int t = threadIdx.x;   // 256
    const float* cl = ws + WS_CLEAF + k * H;
    float acc[KJ];
#pragma unroll
    for (int j = 0; j < KJ; ++j) acc[j] = 0.f;
    for (int h = t; h < H; h += 256) {
        float c = cl[h];
#pragma unroll
        for (int j = 0; j < KJ; ++j) acc[j] += c * Wi[j * H + h];
    }
    __shared__ float red[KJ][256];
#pragma unroll
    for (int j = 0; j < KJ; ++j) red[j][t] = acc[j];
    __syncthreads();
    for (int s = 128; s > 0; s >>= 1) {
        if (t < s) {
#pragma unroll
            for (int j = 0; j < KJ; ++j) red[j][t] += red[j][t + s];
        }
        __syncthreads();
    }
    if (t == 0) {
        float l[KJ], m = -1e30f;
#pragma unroll
        for (int j = 0; j < KJ; ++j) { l[j] = red[j][0] + bi[j]; m = fmaxf(m, l[j]); }
        float s = 0.f;
#pragma unroll
        for (int j = 0; j < KJ; ++j) { l[j] = expf(l[j] - m); s += l[j]; }
        float inv = 1.0f / s;
#pragma unroll
        for (int j = 0; j < KJ; ++j) ws[WS_GATE + k * KJ + j] = l[j] * inv;
    }
}

// ------------- K4: no-leaf einsum partials: c_leaf @ Wn[j] ------------------
// grid (8 j, 4 g-tiles, 8 h-chunks), 256 threads, each thread owns 2 g (float2)
__global__ void k_nl_partial(const float* __restrict__ Wn, float* __restrict__ ws) {
    const int j  = blockIdx.x;
    const int g0 = blockIdx.y * 512;
    const int hc = blockIdx.z;
    const int h0 = hc * 256;
    __shared__ float cls[K0][256];   // 16 KB
    int t = threadIdx.x;
    for (int i = t; i < K0 * 256; i += 256) {
        int k = i >> 8, hh = i & 255;
        cls[k][hh] = ws[WS_CLEAF + k * H + h0 + hh];
    }
    __syncthreads();
    int g = g0 + t * 2;
    const float* Wp = Wn + ((size_t)j * H + h0) * (size_t)H + g;
    float2 acc[K0];
#pragma unroll
    for (int k = 0; k < K0; ++k) { acc[k].x = 0.f; acc[k].y = 0.f; }
#pragma unroll 4
    for (int hh = 0; hh < 256; ++hh) {
        float2 w = *(const float2*)(Wp + (size_t)hh * H);
#pragma unroll
        for (int k = 0; k < K0; ++k) {
            float c = cls[k][hh];
            acc[k].x += c * w.x; acc[k].y += c * w.y;
        }
    }
#pragma unroll
    for (int k = 0; k < K0; ++k)
        *(float2*)(ws + WS_PNL + ((size_t)((hc * KJ + j) * K0 + k) << 11) + g) = acc[k];
}

// ------------- K4b: c_no_leaf[j][g] = sum_k gate[k][j]*tanh(pnl+nb) ---------
__global__ void k_cnl(const float* __restrict__ nb, float* __restrict__ ws) {
    int idx = blockIdx.x * 256 + threadIdx.x;   // 64 blocks -> 16384
    int j = idx >> 11;
    int g = idx & (H - 1);
    float out = 0.f;
#pragma unroll
    for (int k = 0; k < K0; ++k) {
        float s = 0.f;
#pragma unroll
        for (int hc = 0; hc < 8; ++hc)
            s += ws[WS_PNL + ((size_t)((hc * KJ + j) * K0 + k) << 11) + g];
        float u = tanhf(s + nb[j * H + g]);
        out += ws[WS_GATE + k * KJ + j] * u;
    }
    ws[WS_CNL + j * H + g] = out;
}

// ------------- K5: root partials: c_no_leaf @ root_weight_u -----------------
// grid (4 g2-tiles, 32 g-chunks), 256 threads, each thread owns 2 g2 (float2)
__global__ void k_root_partial(const float* __restrict__ Wr, float* __restrict__ ws) {
    const int g2t = blockIdx.x;
    const int gc  = blockIdx.y;
    const int g0  = gc * 64;
    __shared__ float cns[KJ][64];   // 2 KB
    int t = threadIdx.x;
    for (int i = t; i < KJ * 64; i += 256) {
        int j = i >> 6, gg = i & 63;
        cns[j][gg] = ws[WS_CNL + j * H + g0 + gg];
    }
    __syncthreads();
    int g2 = g2t * 512 + t * 2;
    float2 acc[KJ];
#pragma unroll
    for (int j = 0; j < KJ; ++j) { acc[j].x = 0.f; acc[j].y = 0.f; }
#pragma unroll 4
    for (int gg = 0; gg < 64; ++gg) {
        float2 w = *(const float2*)(Wr + (size_t)(g0 + gg) * H + g2);
#pragma unroll
        for (int j = 0; j < KJ; ++j) {
            float c = cns[j][gg];
            acc[j].x += c * w.x; acc[j].y += c * w.y;
        }
    }
#pragma unroll
    for (int j = 0; j < KJ; ++j)
        *(float2*)(ws + WS_PROOT + ((size_t)(gc * KJ + j) << 11) + g2) = acc[j];
}

// ------------- K6: root reduce + tanh + sum over j -> out (x2) --------------
__global__ void k_final(const float* __restrict__ rb, float* __restrict__ ws,
                        float* __restrict__ out) {
    int g2 = blockIdx.x * 256 + threadIdx.x;   // 8 blocks -> 2048
    float tot = 0.f;
#pragma unroll
    for (int j = 0; j < KJ; ++j) {
        float s = 0.f;
#pragma unroll
        for (int gc = 0; gc < 32; ++gc)
            s += ws[WS_PROOT + ((size_t)(gc * KJ + j) << 11) + g2];
        tot += tanhf(s + rb[g2]);
    }
    out[g2] = tot;
    out[2048 + g2] = tot;
}

extern "C" void kernel_launch(void* const* d_in, const int* in_sizes, int n_in,
                              void* d_out, int out_size, void* d_ws, size_t ws_size,
                              hipStream_t stream) {
    const float* x  = (const float*)d_in[0];
    const float* cc = (const float*)d_in[1];
    const float* lw = (const float*)d_in[2];
    const float* lb = (const float*)d_in[3];
    const float* wi = (const float*)d_in[4];
    const float* bi = (const float*)d_in[5];
    const float* wn = (const float*)d_in[6];
    const float* nb = (const float*)d_in[7];
    const float* wr = (const float*)d_in[8];
    const float* rb = (const float*)d_in[9];
    float* out = (float*)d_out;
    float* ws  = (float*)d_ws;

    k_assign      <<<1, 256, 0, stream>>>(x, cc, ws);
    k_leaf_partial<<<dim3(16, 2, 16), 256, 0, stream>>>(x, lw, ws);
    k_cleaf       <<<128, 256, 0, stream>>>(lb, ws);
    k_gate        <<<16, 256, 0, stream>>>(wi, bi, ws);
    k_nl_partial  <<<dim3(8, 4, 8), 256, 0, stream>>>(wn, ws);
    k_cnl         <<<64, 256, 0, stream>>>(nb, ws);
    k_root_partial<<<dim3(4, 32), 256, 0, stream>>>(wr, ws);
    k_final       <<<8, 256, 0, stream>>>(rb, ws, out);
}

// Round 4
// 500.901 us; speedup vs baseline: 1.1896x; 1.1896x over previous
//
#include <hip/hip_runtime.h>
#include <math.h>

// Problem sizes (fixed by reference)
#define D   2048
#define H   2048
#define K0  16
#define KJ  8

// Skip threshold for soft-assignment sparsity. c_leaf[k] = assign[k]*tanh(.)
// with |tanh|<=1, so dropping clusters with assign[k] < 1e-7 perturbs every
// downstream value by <= ~16*1e-7*||W||_1-ish ~ 2e-4, far below the 0.16
// validation threshold. Bounded worst-case, not data-dependent luck.
#define SKIP_THR 1e-7f

// ---- workspace layout (floats) ----
#define WS_ASSIGN 0         // [16]
#define WS_GATE   64        // [16][8]
#define WS_CLEAF  256       // [16][2048]
#define WS_PLEAF  33024     // [32 dc][16 k][2048 h]   = 1,048,576
#define WS_PNL    1081600   // [16 hc][8 j][16 k][2048 g] = 4,194,304
#define WS_CNL    5275904   // [8][2048]
#define WS_PROOT  5292288   // [32 gc][8 j][2048 g2]  = 524,288
#define WS_TMP    5816576   // [8][2048]
// total ~5.83M floats = 23.3 MB

// ---------------- K1: soft assignment, wave-per-cluster ---------------------
__global__ void k_assign(const float* __restrict__ x, const float* __restrict__ cc,
                         float* __restrict__ ws) {
    int t = threadIdx.x, w = t >> 6, l = t & 63;   // 1024 thr = 16 waves
    const float4* c4 = (const float4*)(cc + w * D);
    const float4* x4 = (const float4*)x;
    float a = 0.f;
#pragma unroll
    for (int i = 0; i < 8; ++i) {
        float4 xv = x4[l + i * 64];
        float4 cv = c4[l + i * 64];
        float dx = xv.x - cv.x, dy = xv.y - cv.y;
        float dz = xv.z - cv.z, dw = xv.w - cv.w;
        a += dx * dx + dy * dy + dz * dz + dw * dw;
    }
#pragma unroll
    for (int off = 32; off > 0; off >>= 1) a += __shfl_down(a, off);
    __shared__ float sq[K0];
    if (l == 0) sq[w] = a;
    __syncthreads();
    if (t == 0) {
        float v[K0], m = -1e30f;
#pragma unroll
        for (int k = 0; k < K0; ++k) { v[k] = -sq[k] * 0.1f; m = fmaxf(m, v[k]); }
        float s = 0.f;
#pragma unroll
        for (int k = 0; k < K0; ++k) { v[k] = expf(v[k] - m); s += v[k]; }
        float inv = 1.0f / s;
#pragma unroll
        for (int k = 0; k < K0; ++k) ws[WS_ASSIGN + k] = v[k] * inv;
    }
}

// ------------- K2: leaf einsum partials (with cluster skip) -----------------
// grid (16 k, 2 h-tiles, 32 d-chunks of 64), 256 threads, 4 h per thread
__global__ void k_leaf_partial(const float* __restrict__ x, const float* __restrict__ W,
                               float* __restrict__ ws) {
    const int k = blockIdx.x;
    if (ws[WS_ASSIGN + k] < SKIP_THR) return;   // whole slab unneeded
    const int h0 = blockIdx.y * 1024;
    const int d0 = blockIdx.z * 64;
    __shared__ float xs[64];
    int t = threadIdx.x;
    if (t < 64) xs[t] = x[d0 + t];
    __syncthreads();
    int h = h0 + t * 4;
    const float* Wp = W + ((size_t)k * D + d0) * (size_t)H + h;
    float4 acc = make_float4(0.f, 0.f, 0.f, 0.f);
#pragma unroll 16
    for (int dd = 0; dd < 64; ++dd) {
        float4 w = *(const float4*)(Wp + (size_t)dd * H);
        float xv = xs[dd];
        acc.x += xv * w.x; acc.y += xv * w.y; acc.z += xv * w.z; acc.w += xv * w.w;
    }
    *(float4*)(ws + WS_PLEAF + ((size_t)(blockIdx.z * K0 + k) << 11) + h) = acc;
}

// ------------- K3a: c_leaf = assign * tanh(sum(partials)+bias) --------------
__global__ void k_cleaf(const float* __restrict__ lb, float* __restrict__ ws) {
    int idx = blockIdx.x * 256 + threadIdx.x;   // 128 blocks -> 32768
    int k = idx >> 11, h = idx & (H - 1);
    float az = ws[WS_ASSIGN + k];
    float v = 0.f;
    if (az >= SKIP_THR) {
        float s = 0.f;
#pragma unroll
        for (int dc = 0; dc < 32; ++dc)
            s += ws[WS_PLEAF + ((size_t)(dc * K0 + k) << 11) + h];
        v = tanhf(s + lb[k * H + h]) * az;
    }
    ws[WS_CLEAF + k * H + h] = v;
}

// ------------- K3b: gate = softmax_j(c_leaf[k] . Wi[j] + bi[j]) -------------
__global__ void k_gate(const float* __restrict__ Wi, const float* __restrict__ bi,
                       float* __restrict__ ws) {
    int k = blockIdx.x;    // 16 blocks
    int t = threadIdx.x;   // 256
    const float* cl = ws + WS_CLEAF + k * H;
    float acc[KJ];
#pragma unroll
    for (int j = 0; j < KJ; ++j) acc[j] = 0.f;
    for (int h = t; h < H; h += 256) {
        float c = cl[h];
#pragma unroll
        for (int j = 0; j < KJ; ++j) acc[j] += c * Wi[j * H + h];
    }
    __shared__ float red[KJ][256];
#pragma unroll
    for (int j = 0; j < KJ; ++j) red[j][t] = acc[j];
    __syncthreads();
    for (int s = 128; s > 0; s >>= 1) {
        if (t < s) {
#pragma unroll
            for (int j = 0; j < KJ; ++j) red[j][t] += red[j][t + s];
        }
        __syncthreads();
    }
    if (t == 0) {
        float l[KJ], m = -1e30f;
#pragma unroll
        for (int j = 0; j < KJ; ++j) { l[j] = red[j][0] + bi[j]; m = fmaxf(m, l[j]); }
        float s = 0.f;
#pragma unroll
        for (int j = 0; j < KJ; ++j) { l[j] = expf(l[j] - m); s += l[j]; }
        float inv = 1.0f / s;
#pragma unroll
        for (int j = 0; j < KJ; ++j) ws[WS_GATE + k * KJ + j] = l[j] * inv;
    }
}

// ------------- K4: no-leaf einsum partials: c_leaf @ Wn[j] ------------------
// grid (8 j, 4 g-tiles, 16 h-chunks of 128), 256 threads, 2 g per thread
__global__ void k_nl_partial(const float* __restrict__ Wn, float* __restrict__ ws) {
    const int j  = blockIdx.x;
    const int g0 = blockIdx.y * 512;
    const int h0 = blockIdx.z * 128;
    __shared__ float cls[K0][128];   // 8 KB
    int t = threadIdx.x;
    for (int i = t; i < K0 * 128; i += 256) {
        int k = i >> 7, hh = i & 127;
        cls[k][hh] = ws[WS_CLEAF + k * H + h0 + hh];
    }
    __syncthreads();
    int g = g0 + t * 2;
    const float* Wp = Wn + ((size_t)j * H + h0) * (size_t)H + g;
    float2 acc[K0];
#pragma unroll
    for (int k = 0; k < K0; ++k) { acc[k].x = 0.f; acc[k].y = 0.f; }
#pragma unroll 8
    for (int hh = 0; hh < 128; ++hh) {
        float2 w = *(const float2*)(Wp + (size_t)hh * H);
#pragma unroll
        for (int k = 0; k < K0; ++k) {
            float c = cls[k][hh];
            acc[k].x += c * w.x; acc[k].y += c * w.y;
        }
    }
#pragma unroll
    for (int k = 0; k < K0; ++k)
        *(float2*)(ws + WS_PNL + ((size_t)((blockIdx.z * KJ + j) * K0 + k) << 11) + g) = acc[k];
}

// ------------- K4b: c_no_leaf[j][g] = sum_k gate[k][j]*tanh(pnl+nb) ---------
__global__ void k_cnl(const float* __restrict__ nb, float* __restrict__ ws) {
    int idx = blockIdx.x * 128 + threadIdx.x;   // 128 blocks x 128 -> 16384
    int j = idx >> 11, g = idx & (H - 1);
    float bias = nb[j * H + g];
    float out = 0.f;
#pragma unroll
    for (int k = 0; k < K0; ++k) {
        float s = 0.f;
#pragma unroll
        for (int hc = 0; hc < 16; ++hc)
            s += ws[WS_PNL + ((size_t)((hc * KJ + j) * K0 + k) << 11) + g];
        out += ws[WS_GATE + k * KJ + j] * tanhf(s + bias);
    }
    ws[WS_CNL + j * H + g] = out;
}

// ------------- K5: root partials: c_no_leaf @ root_weight_u -----------------
// grid (4 g2-tiles, 32 g-chunks of 64), 256 threads, 2 g2 per thread
__global__ void k_root_partial(const float* __restrict__ Wr, float* __restrict__ ws) {
    const int g2t = blockIdx.x;
    const int g0  = blockIdx.y * 64;
    __shared__ float cns[KJ][64];   // 2 KB
    int t = threadIdx.x;
    for (int i = t; i < KJ * 64; i += 256) {
        int j = i >> 6, gg = i & 63;
        cns[j][gg] = ws[WS_CNL + j * H + g0 + gg];
    }
    __syncthreads();
    int g2 = g2t * 512 + t * 2;
    float2 acc[KJ];
#pragma unroll
    for (int j = 0; j < KJ; ++j) { acc[j].x = 0.f; acc[j].y = 0.f; }
#pragma unroll 8
    for (int gg = 0; gg < 64; ++gg) {
        float2 w = *(const float2*)(Wr + (size_t)(g0 + gg) * H + g2);
#pragma unroll
        for (int j = 0; j < KJ; ++j) {
            float c = cns[j][gg];
            acc[j].x += c * w.x; acc[j].y += c * w.y;
        }
    }
#pragma unroll
    for (int j = 0; j < KJ; ++j)
        *(float2*)(ws + WS_PROOT + ((size_t)(blockIdx.y * KJ + j) << 11) + g2) = acc[j];
}

// ------------- K6a: root tanh: tmp[j][g2] = tanh(sum_gc proot + rb) ---------
__global__ void k_root_tanh(const float* __restrict__ rb, float* __restrict__ ws) {
    int j  = blockIdx.x;                        // 8
    int g2 = blockIdx.y * 256 + threadIdx.x;    // 8 x 256
    float s = 0.f;
#pragma unroll
    for (int gc = 0; gc < 32; ++gc)
        s += ws[WS_PROOT + ((size_t)(gc * KJ + j) << 11) + g2];
    ws[WS_TMP + j * H + g2] = tanhf(s + rb[g2]);
}

// ------------- K6b: out = sum_j tmp (duplicated) ----------------------------
__global__ void k_final(float* __restrict__ ws, float* __restrict__ out) {
    int g2 = blockIdx.x * 256 + threadIdx.x;    // 8 x 256
    float tot = 0.f;
#pragma unroll
    for (int j = 0; j < KJ; ++j) tot += ws[WS_TMP + j * H + g2];
    out[g2] = tot;
    out[H + g2] = tot;
}

extern "C" void kernel_launch(void* const* d_in, const int* in_sizes, int n_in,
                              void* d_out, int out_size, void* d_ws, size_t ws_size,
                              hipStream_t stream) {
    const float* x  = (const float*)d_in[0];
    const float* cc = (const float*)d_in[1];
    const float* lw = (const float*)d_in[2];
    const float* lb = (const float*)d_in[3];
    const float* wi = (const float*)d_in[4];
    const float* bi = (const float*)d_in[5];
    const float* wn = (const float*)d_in[6];
    const float* nb = (const float*)d_in[7];
    const float* wr = (const float*)d_in[8];
    const float* rb = (const float*)d_in[9];
    float* out = (float*)d_out;
    float* ws  = (float*)d_ws;

    k_assign      <<<1, 1024, 0, stream>>>(x, cc, ws);
    k_leaf_partial<<<dim3(16, 2, 32), 256, 0, stream>>>(x, lw, ws);
    k_cleaf       <<<128, 256, 0, stream>>>(lb, ws);
    k_gate        <<<16, 256, 0, stream>>>(wi, bi, ws);
    k_nl_partial  <<<dim3(8, 4, 16), 256, 0, stream>>>(wn, ws);
    k_cnl         <<<128, 128, 0, stream>>>(nb, ws);
    k_root_partial<<<dim3(4, 32), 256, 0, stream>>>(wr, ws);
    k_root_tanh   <<<dim3(8, 8), 256, 0, stream>>>(rb, ws);
    k_final       <<<8, 256, 0, stream>>>(ws, out);
}